// Round 1
// baseline (35963.373 us; speedup 1.0000x reference)
//
#include <hip/hip_runtime.h>
#include <hip/hip_bf16.h>

#if __has_builtin(__builtin_amdgcn_exp2f)
#define EXP2F(x) __builtin_amdgcn_exp2f(x)
#else
#define EXP2F(x) exp2f(x)
#endif
#if __has_builtin(__builtin_amdgcn_rcpf)
#define RCPF(x) __builtin_amdgcn_rcpf(x)
#else
#define RCPF(x) (1.0f/(x))
#endif

namespace {
constexpr int   kT   = 127;
constexpr int   kE   = 128;
constexpr int   kB   = 4096;
constexpr int   kNWG = 512;
constexpr int   kBPW = kB / kNWG;          // 8 batch elements per workgroup
constexpr float kLog2e = 1.4426950408889634f;
constexpr float kK2    = 2.8853900817779268f;   // 2*log2(e)
constexpr int   kSmemBytes = 77360;

__device__ __forceinline__ float bf2f(unsigned short u) {
  return __uint_as_float(((unsigned int)u) << 16);
}
__device__ __forceinline__ unsigned short f2bf(float f) {
  unsigned int x = __float_as_uint(f);
  return (unsigned short)((x + 0x7fffu + ((x >> 16) & 1u)) >> 16);
}

__device__ __forceinline__ float redsum64(float a) {
#pragma unroll
  for (int m = 1; m < 64; m <<= 1) a += __shfl_xor(a, m, 64);
  return a;
}
__device__ __forceinline__ float redmax64(float a) {
#pragma unroll
  for (int m = 1; m < 64; m <<= 1) a = fmaxf(a, __shfl_xor(a, m, 64));
  return a;
}

__global__ __launch_bounds__(1024, 8) void decoder_kernel(
    const float* __restrict__ Xg,    // [B,127,128] input_encoded
    const float* __restrict__ yh,    // [B,127]
    const float* __restrict__ vdw,   // [128]
    const float* __restrict__ vdb,   // [1]
    const float* __restrict__ Wdhs,  // [128,256]
    const float* __restrict__ Wdhsb, // [128]
    const float* __restrict__ Udw,   // [128,128]
    const float* __restrict__ Udb,   // [128]
    const float* __restrict__ ww,    // [129]
    const float* __restrict__ wb,    // [1]
    const float* __restrict__ Wih,   // [512]
    const float* __restrict__ Whh,   // [512,128]
    const float* __restrict__ bih,   // [512]
    const float* __restrict__ bhh,   // [512]
    const float* __restrict__ fcww,  // [256]
    const float* __restrict__ fcb,   // [1]
    float* __restrict__ out)         // [B]
{
  extern __shared__ char smem[];
  unsigned short* u2   = (unsigned short*)smem;              // [128][128] bf16 (K2-prescaled U)
  unsigned short* xb   = (unsigned short*)(smem + 32768);    // [128][128] bf16 X
  float* hc    = (float*)(smem + 65536);  // [256]  h then c
  float* p2    = hc    + 256;             // [128]
  float* sc    = p2    + 128;             // [128]
  float* beta  = sc    + 128;             // [128]
  float* part  = beta  + 128;             // [8*128]
  float* act   = part  + 1024;            // [512]  (also gate-partials alias)
  float* ctxl  = act   + 512;             // [128]
  float* wwl   = ctxl  + 128;             // [132]  w_w(129) + w_b at [129]
  float* fcw   = wwl   + 132;             // [256]
  float* wdb_l = fcw   + 256;             // [128]  W_dhs_b
  float* yrow  = wdb_l + 128;             // [128]
  float* scal  = yrow  + 128;             // [8]    [0]=C0, [1]=y_tilde

  const int tid = threadIdx.x;
  const int g   = tid & 511;          // gate index role
  const int dh  = tid >> 9;           // d-half for W_hh
  const int e1  = tid & 127;          // e index role
  const int ck  = (tid >> 7) & 7;     // 32-col chunk (proj) / 16-t chunk (ctx)
  const int ts  = tid >> 3;           // t for scores (valid < 127)
  const int ec  = (tid & 7) * 16;     // e chunk for scores

  // ---- persistent per-lane weights in VGPRs ----
  float whhr[64];
#pragma unroll
  for (int k = 0; k < 64; ++k) whhr[k] = Whh[g * 128 + dh * 64 + k];
  float wdr[32];
#pragma unroll
  for (int j = 0; j < 32; ++j) wdr[j] = Wdhs[e1 * 256 + ck * 32 + j];
  float v2r[16];
#pragma unroll
  for (int j = 0; j < 16; ++j) v2r[j] = -2.0f * vdw[ec + j];
  const float bihh = bih[g] + bhh[g];
  const float wihr = Wih[g];

  // ---- one-time constants to LDS ----
  if (tid < 129) wwl[tid] = ww[tid];
  if (tid == 0)  wwl[129] = wb[0];
  if (tid < 256) fcw[tid] = fcww[tid];
  if (tid < 128) wdb_l[tid] = Wdhsb[tid];
  if (tid < 64) {
    float a = vdw[tid] + vdw[tid + 64];
    a = redsum64(a);
    if (tid == 0) scal[0] = a + vdb[0];   // C0 = sum(v) + v_b
  }

  for (int bi = 0; bi < kBPW; ++bi) {
    const int b = blockIdx.x * kBPW + bi;
    const float* Xb = Xg + (size_t)b * (kT * kE);
    __syncthreads();   // previous batch done with LDS

    // ---- stage X (bf16) ----
    for (int i = tid; i < kT * kE; i += 1024) xb[i] = f2bf(Xb[i]);
    if (tid < 128) xb[127 * 128 + tid] = 0;     // zero pad row (beta[127]==0)
    if (tid < kT)  yrow[tid] = yh[b * kT + tid];
    if (tid < 256) hc[tid] = 0.0f;
    __syncthreads();

    // ---- compute U2 = K2*(X @ Udw^T + Udb), bf16 in LDS ----
    if (ts < kT) {
      float acc[16];
#pragma unroll
      for (int j = 0; j < 16; ++j) acc[j] = 0.0f;
      for (int k0 = 0; k0 < 128; k0 += 8) {
        const uint4 u = *(const uint4*)&xb[ts * 128 + k0];
        float xv[8];
        xv[0] = bf2f((unsigned short)(u.x & 0xffffu));
        xv[1] = bf2f((unsigned short)(u.x >> 16));
        xv[2] = bf2f((unsigned short)(u.y & 0xffffu));
        xv[3] = bf2f((unsigned short)(u.y >> 16));
        xv[4] = bf2f((unsigned short)(u.z & 0xffffu));
        xv[5] = bf2f((unsigned short)(u.z >> 16));
        xv[6] = bf2f((unsigned short)(u.w & 0xffffu));
        xv[7] = bf2f((unsigned short)(u.w >> 16));
#pragma unroll
        for (int j = 0; j < 16; ++j) {
          const float4* wp = (const float4*)&Udw[(ec + j) * 128 + k0];
          const float4 w0 = wp[0], w1 = wp[1];
          acc[j] += xv[0]*w0.x + xv[1]*w0.y + xv[2]*w0.z + xv[3]*w0.w
                  + xv[4]*w1.x + xv[5]*w1.y + xv[6]*w1.z + xv[7]*w1.w;
        }
      }
#pragma unroll
      for (int j = 0; j < 16; ++j)
        u2[ts * 128 + ec + j] = f2bf(kK2 * (acc[j] + Udb[ec + j]));
    }
    __syncthreads();

    // ================= 127 recurrent steps =================
    for (int s = 0; s < kT; ++s) {
      // P1: proj partials (W_dhs) + gate partials (W_hh), h/c via uniform LDS broadcast
      float pacc = 0.0f;
#pragma unroll
      for (int q = 0; q < 8; ++q) {
        const float4 h4 = *(const float4*)&hc[ck * 32 + q * 4];
        pacc += wdr[q*4+0]*h4.x + wdr[q*4+1]*h4.y + wdr[q*4+2]*h4.z + wdr[q*4+3]*h4.w;
      }
      part[ck * 128 + e1] = pacc;
      float gacc = 0.0f;
#pragma unroll
      for (int q = 0; q < 16; ++q) {
        const float4 h4 = *(const float4*)&hc[dh * 64 + q * 4];
        gacc += whhr[q*4+0]*h4.x + whhr[q*4+1]*h4.y + whhr[q*4+2]*h4.z + whhr[q*4+3]*h4.w;
      }
      if (dh) act[g] = gacc;          // act[] doubles as gate-partial buffer
      __syncthreads();

      // P2: reduce proj -> p2 (prescaled), combine gate halves into reg
      float ghsum = 0.0f;
      if (tid < 512) ghsum = gacc + act[g] + bihh;
      if (tid < 128) {
        float ps = wdb_l[tid];
#pragma unroll
        for (int k = 0; k < 8; ++k) ps += part[k * 128 + tid];
        p2[tid] = kK2 * ps;
      }
      __syncthreads();

      // P3: scores[t] = C0 - 2*sum_e v[e] * rcp(1 + exp2(p2[e] + U2[t][e]))
      if (ts < kT) {
        const float4 pa = *(const float4*)&p2[ec + 0];
        const float4 pb = *(const float4*)&p2[ec + 4];
        const float4 pc4 = *(const float4*)&p2[ec + 8];
        const float4 pd4 = *(const float4*)&p2[ec + 12];
        const float pv[16] = {pa.x, pa.y, pa.z, pa.w, pb.x, pb.y, pb.z, pb.w,
                              pc4.x, pc4.y, pc4.z, pc4.w, pd4.x, pd4.y, pd4.z, pd4.w};
        const uint4 ua = *(const uint4*)&u2[ts * 128 + ec];
        const uint4 ub = *(const uint4*)&u2[ts * 128 + ec + 8];
        const unsigned int uu[8] = {ua.x, ua.y, ua.z, ua.w, ub.x, ub.y, ub.z, ub.w};
        float sacc = 0.0f;
#pragma unroll
        for (int q = 0; q < 8; ++q) {
          const float x0 = bf2f((unsigned short)(uu[q] & 0xffffu)) + pv[2*q];
          const float x1 = bf2f((unsigned short)(uu[q] >> 16))     + pv[2*q+1];
          const float r0 = RCPF(1.0f + EXP2F(x0));
          const float r1 = RCPF(1.0f + EXP2F(x1));
          sacc += v2r[2*q] * r0 + v2r[2*q+1] * r1;
        }
        sacc += __shfl_xor(sacc, 1, 64);
        sacc += __shfl_xor(sacc, 2, 64);
        sacc += __shfl_xor(sacc, 4, 64);
        if ((tid & 7) == 0) sc[ts] = sacc + scal[0];
      }
      __syncthreads();

      // P4: softmax over t (wave 0)
      if (tid < 64) {
        const float s0 = sc[tid];
        const float s1 = (tid + 64 < kT) ? sc[tid + 64] : -3.0e38f;
        float m = fmaxf(s0, s1);
        m = redmax64(m);
        const float e0  = EXP2F((s0 - m) * kLog2e);
        const float e1x = (tid + 64 < kT) ? EXP2F((s1 - m) * kLog2e) : 0.0f;
        float sum = e0 + e1x;
        sum = redsum64(sum);
        const float rs = RCPF(sum);
        beta[tid]      = e0  * rs;
        beta[tid + 64] = e1x * rs;     // beta[127] = 0
      }
      __syncthreads();

      // P5: ctx partials: lane e1 accumulates over a 16-t chunk
      {
        float cacc = 0.0f;
#pragma unroll
        for (int q = 0; q < 4; ++q) {
          const float4 b4 = *(const float4*)&beta[ck * 16 + q * 4];
          const int t0 = ck * 16 + q * 4;
          const float x0 = bf2f(xb[(t0 + 0) * 128 + e1]);
          const float x1 = bf2f(xb[(t0 + 1) * 128 + e1]);
          const float x2 = bf2f(xb[(t0 + 2) * 128 + e1]);
          const float x3 = bf2f(xb[(t0 + 3) * 128 + e1]);
          cacc += b4.x*x0 + b4.y*x1 + b4.z*x2 + b4.w*x3;
        }
        part[ck * 128 + e1] = cacc;
      }
      __syncthreads();

      // P6: ctx reduce (lanes 0-127) || y_tilde from partials (wave 2)
      if (tid < 128) {
        float cs = 0.0f;
#pragma unroll
        for (int k = 0; k < 8; ++k) cs += part[k * 128 + tid];
        ctxl[tid] = cs;
      }
      if (tid >= 128 && tid < 192) {
        const int l = tid - 128;
        float ya = 0.0f;
#pragma unroll
        for (int k = 0; k < 8; ++k)
          ya += part[k * 128 + l] * wwl[l] + part[k * 128 + l + 64] * wwl[l + 64];
        ya = redsum64(ya);
        if (l == 0) scal[1] = ya + wwl[128] * yrow[s] + wwl[129];
      }
      __syncthreads();

      // P7: gate nonlinearities (role uniform per wave: i,f,g~,o)
      if (tid < 512) {
        const float gate = ghsum + scal[1] * wihr;
        const int role = tid >> 7;
        float a;
        if (role == 2) {  // tanh
          a = 1.0f - 2.0f * RCPF(1.0f + EXP2F(gate * kK2));
        } else {          // sigmoid
          a = RCPF(1.0f + EXP2F(-gate * kLog2e));
        }
        act[tid] = a;
      }
      __syncthreads();

      // P8: LSTM state update
      if (tid < 128) {
        const float cold = hc[128 + tid];
        const float cn = act[128 + tid] * cold + act[tid] * act[256 + tid];
        const float th = 1.0f - 2.0f * RCPF(1.0f + EXP2F(cn * kK2));
        hc[tid] = act[384 + tid] * th;
        hc[128 + tid] = cn;
      }
      __syncthreads();
    }  // steps

    // ---- final ctx in fp32 from global X (protects the direct fc path) ----
    {
      float cacc = 0.0f;
#pragma unroll
      for (int q = 0; q < 16; ++q) {
        const int t = ck * 16 + q;
        if (t < kT) cacc += beta[t] * Xb[t * 128 + e1];
      }
      part[ck * 128 + e1] = cacc;
    }
    __syncthreads();
    if (tid < 128) {
      float cs = 0.0f;
#pragma unroll
      for (int k = 0; k < 8; ++k) cs += part[k * 128 + tid];
      ctxl[tid] = cs;
    }
    __syncthreads();
    if (tid < 64) {
      float a = hc[tid] * fcw[tid] + hc[tid + 64] * fcw[tid + 64]
              + ctxl[tid] * fcw[128 + tid] + ctxl[tid + 64] * fcw[192 + tid];
      a = redsum64(a);
      if (tid == 0) out[b] = a + fcb[0];
    }
  }  // batch loop
}
}  // namespace

extern "C" void kernel_launch(void* const* d_in, const int* in_sizes, int n_in,
                              void* d_out, int out_size, void* d_ws, size_t ws_size,
                              hipStream_t stream) {
  (void)in_sizes; (void)n_in; (void)d_ws; (void)ws_size; (void)out_size;
  const float* Xg    = (const float*)d_in[0];
  const float* yh    = (const float*)d_in[1];
  const float* vdw   = (const float*)d_in[2];
  const float* vdb   = (const float*)d_in[3];
  const float* Wdhs  = (const float*)d_in[4];
  const float* Wdhsb = (const float*)d_in[5];
  const float* Udw   = (const float*)d_in[6];
  const float* Udb   = (const float*)d_in[7];
  const float* ww    = (const float*)d_in[8];
  const float* wb    = (const float*)d_in[9];
  const float* Wih   = (const float*)d_in[10];
  const float* Whh   = (const float*)d_in[11];
  const float* bih   = (const float*)d_in[12];
  const float* bhh   = (const float*)d_in[13];
  const float* fcww  = (const float*)d_in[14];
  const float* fcb   = (const float*)d_in[15];
  float* out = (float*)d_out;

  hipFuncSetAttribute((const void*)decoder_kernel,
                      hipFuncAttributeMaxDynamicSharedMemorySize, kSmemBytes);
  decoder_kernel<<<dim3(kNWG), dim3(1024), kSmemBytes, stream>>>(
      Xg, yh, vdw, vdb, Wdhs, Wdhsb, Udw, Udb, ww, wb,
      Wih, Whh, bih, bhh, fcww, fcb, out);
}

// Round 2
// 23674.541 us; speedup vs baseline: 1.5191x; 1.5191x over previous
//
#include <hip/hip_runtime.h>
#include <hip/hip_bf16.h>

#if __has_builtin(__builtin_amdgcn_exp2f)
#define EXP2F(x) __builtin_amdgcn_exp2f(x)
#else
#define EXP2F(x) exp2f(x)
#endif
#if __has_builtin(__builtin_amdgcn_rcpf)
#define RCPF(x) __builtin_amdgcn_rcpf(x)
#else
#define RCPF(x) (1.0f/(x))
#endif

namespace {
constexpr int   kT   = 127;
constexpr int   kE   = 128;
constexpr int   kB   = 4096;
constexpr int   kNWG = 256;
constexpr int   kBPW = kB / kNWG;          // 16 batch elements per workgroup
constexpr float kLog2e = 1.4426950408889634f;
constexpr float kK2    = 2.8853900817779268f;   // 2*log2(e)
constexpr int   kSmemBytes = 77872;

__device__ __forceinline__ float bf2f(unsigned short u) {
  return __uint_as_float(((unsigned int)u) << 16);
}
__device__ __forceinline__ unsigned short f2bf(float f) {
  unsigned int x = __float_as_uint(f);
  return (unsigned short)((x + 0x7fffu + ((x >> 16) & 1u)) >> 16);
}

__device__ __forceinline__ float redsum64(float a) {
#pragma unroll
  for (int m = 1; m < 64; m <<= 1) a += __shfl_xor(a, m, 64);
  return a;
}
__device__ __forceinline__ float redmax64(float a) {
#pragma unroll
  for (int m = 1; m < 64; m <<= 1) a = fmaxf(a, __shfl_xor(a, m, 64));
  return a;
}

__global__ __launch_bounds__(1024, 4) void decoder_kernel(
    const float* __restrict__ Xg,    // [B,127,128] input_encoded
    const float* __restrict__ yh,    // [B,127]
    const float* __restrict__ vdw,   // [128]
    const float* __restrict__ vdb,   // [1]
    const float* __restrict__ Wdhs,  // [128,256]
    const float* __restrict__ Wdhsb, // [128]
    const float* __restrict__ Udw,   // [128,128]
    const float* __restrict__ Udb,   // [128]
    const float* __restrict__ ww,    // [129]
    const float* __restrict__ wb,    // [1]
    const float* __restrict__ Wih,   // [512]
    const float* __restrict__ Whh,   // [512,128]
    const float* __restrict__ bih,   // [512]
    const float* __restrict__ bhh,   // [512]
    const float* __restrict__ fcww,  // [256]
    const float* __restrict__ fcb,   // [1]
    float* __restrict__ out)         // [B]
{
  extern __shared__ char smem[];
  unsigned short* u2   = (unsigned short*)smem;              // [128][128] bf16 (K2-prescaled U, XOR-swizzled 16B chunks)
  unsigned short* xb   = (unsigned short*)(smem + 32768);    // [128][128] bf16 X
  float* hc    = (float*)(smem + 65536);  // [256]  h then c
  float* p2    = hc    + 256;             // [128]
  float* sc    = p2    + 128;             // [128]
  float* beta  = sc    + 128;             // [128]
  float* part  = beta  + 128;             // [8*128]
  float* act   = part  + 1024;            // [512]  (also gate-partials alias)
  float* ctxl  = act   + 512;             // [128]
  float* wwl   = ctxl  + 128;             // [132]  w_w(129) + w_b at [129]
  float* fcw   = wwl   + 132;             // [256]
  float* wdb_l = fcw   + 256;             // [128]  W_dhs_b
  float* yrow  = wdb_l + 128;             // [128]
  float* scal  = yrow  + 128;             // [8]    [0]=C0, [1]=y_tilde
  float* v2l   = scal  + 8;               // [128]  -2*v_d

  const int tid = threadIdx.x;
  const int g   = tid & 511;          // gate index role
  const int dh  = tid >> 9;           // d-half for W_hh
  const int e1  = tid & 127;          // e index role
  const int ck  = (tid >> 7) & 7;     // 32-col chunk (proj) / 16-t chunk (ctx)
  const int ts  = tid >> 3;           // t for scores (valid < 127)
  const int ec  = (tid & 7) * 16;     // e chunk for scores

  // ---- persistent per-lane weights in VGPRs (98 regs, pinned) ----
  float whhr[64];
#pragma unroll
  for (int k = 0; k < 64; ++k) whhr[k] = Whh[g * 128 + dh * 64 + k];
  float wdr[32];
#pragma unroll
  for (int j = 0; j < 32; ++j) wdr[j] = Wdhs[e1 * 256 + ck * 32 + j];
  float bihh = bih[g] + bhh[g];
  float wihr = Wih[g];
  // pin: make values opaque so the compiler cannot rematerialize as global loads
#pragma unroll
  for (int k = 0; k < 64; ++k) asm volatile("" : "+v"(whhr[k]));
#pragma unroll
  for (int j = 0; j < 32; ++j) asm volatile("" : "+v"(wdr[j]));
  asm volatile("" : "+v"(bihh));
  asm volatile("" : "+v"(wihr));

  // ---- one-time constants to LDS ----
  if (tid < 129) wwl[tid] = ww[tid];
  if (tid == 0)  wwl[129] = wb[0];
  if (tid < 256) fcw[tid] = fcww[tid];
  if (tid < 128) wdb_l[tid] = Wdhsb[tid];
  if (tid < 128) v2l[tid] = -2.0f * vdw[tid];
  if (tid < 64) {
    float a = vdw[tid] + vdw[tid + 64];
    a = redsum64(a);
    if (tid == 0) scal[0] = a + vdb[0];   // C0 = sum(v) + v_b
  }

  for (int bi = 0; bi < kBPW; ++bi) {
    const int b = blockIdx.x * kBPW + bi;
    const float* Xb = Xg + (size_t)b * (kT * kE);
    __syncthreads();   // previous batch done with LDS

    // ---- stage X (bf16) ----
    for (int i = tid; i < kT * kE; i += 1024) xb[i] = f2bf(Xb[i]);
    if (tid < 128) xb[127 * 128 + tid] = 0;     // zero pad row (beta[127]==0)
    if (tid < kT)  yrow[tid] = yh[b * kT + tid];
    if (tid < 256) hc[tid] = 0.0f;
    __syncthreads();

    // ---- compute U2 = K2*(X @ Udw^T + Udb), bf16 in LDS, swizzled ----
    if (ts < kT) {
      const int ts7 = ts & 7;
#pragma unroll
      for (int jh = 0; jh < 2; ++jh) {
        float acc[8];
#pragma unroll
        for (int j = 0; j < 8; ++j) acc[j] = 0.0f;
        for (int k0 = 0; k0 < 128; k0 += 8) {
          const uint4 u = *(const uint4*)&xb[ts * 128 + k0];
          float xv[8];
          xv[0] = bf2f((unsigned short)(u.x & 0xffffu));
          xv[1] = bf2f((unsigned short)(u.x >> 16));
          xv[2] = bf2f((unsigned short)(u.y & 0xffffu));
          xv[3] = bf2f((unsigned short)(u.y >> 16));
          xv[4] = bf2f((unsigned short)(u.z & 0xffffu));
          xv[5] = bf2f((unsigned short)(u.z >> 16));
          xv[6] = bf2f((unsigned short)(u.w & 0xffffu));
          xv[7] = bf2f((unsigned short)(u.w >> 16));
#pragma unroll
          for (int j = 0; j < 8; ++j) {
            const float4* wp = (const float4*)&Udw[(ec + jh * 8 + j) * 128 + k0];
            const float4 w0 = wp[0], w1 = wp[1];
            acc[j] += xv[0]*w0.x + xv[1]*w0.y + xv[2]*w0.z + xv[3]*w0.w
                    + xv[4]*w1.x + xv[5]*w1.y + xv[6]*w1.z + xv[7]*w1.w;
          }
        }
        const int c = (ec >> 3) + jh;          // 8-elem chunk index
        const int base = ts * 128 + ((c ^ ts7) << 3);
#pragma unroll
        for (int j = 0; j < 8; ++j)
          u2[base + j] = f2bf(kK2 * (acc[j] + Udb[ec + jh * 8 + j]));
      }
    }
    __syncthreads();

    // ================= 127 recurrent steps =================
    for (int s = 0; s < kT; ++s) {
      // P1: proj partials (W_dhs) + gate partials (W_hh), h/c via uniform LDS broadcast
      float pacc = 0.0f;
#pragma unroll
      for (int q = 0; q < 8; ++q) {
        const float4 h4 = *(const float4*)&hc[ck * 32 + q * 4];
        pacc += wdr[q*4+0]*h4.x + wdr[q*4+1]*h4.y + wdr[q*4+2]*h4.z + wdr[q*4+3]*h4.w;
      }
      part[ck * 128 + e1] = pacc;
      float gacc = 0.0f;
#pragma unroll
      for (int q = 0; q < 16; ++q) {
        const float4 h4 = *(const float4*)&hc[dh * 64 + q * 4];
        gacc += whhr[q*4+0]*h4.x + whhr[q*4+1]*h4.y + whhr[q*4+2]*h4.z + whhr[q*4+3]*h4.w;
      }
      if (dh) act[g] = gacc;          // act[] doubles as gate-partial buffer
      __syncthreads();

      // P2: reduce proj -> p2 (prescaled), combine gate halves into reg
      float ghsum = 0.0f;
      if (tid < 512) ghsum = gacc + act[g] + bihh;
      if (tid < 128) {
        float ps = wdb_l[tid];
#pragma unroll
        for (int k = 0; k < 8; ++k) ps += part[k * 128 + tid];
        p2[tid] = kK2 * ps;
      }
      __syncthreads();

      // P3: scores[t] = C0 - 2*sum_e v[e] * rcp(1 + exp2(p2[e] + U2[t][e]))
      if (ts < kT) {
        const int ts7 = ts & 7;
        const int c0 = (tid & 7) * 2;
        float sacc = 0.0f;
#pragma unroll
        for (int qh = 0; qh < 2; ++qh) {
          const uint4 uq = *(const uint4*)&u2[ts * 128 + (((c0 + qh) ^ ts7) << 3)];
          const float4 pa = *(const float4*)&p2[ec + qh * 8];
          const float4 pb = *(const float4*)&p2[ec + qh * 8 + 4];
          const float4 va = *(const float4*)&v2l[ec + qh * 8];
          const float4 vb = *(const float4*)&v2l[ec + qh * 8 + 4];
          const unsigned int uu[4] = {uq.x, uq.y, uq.z, uq.w};
          const float pv[8] = {pa.x, pa.y, pa.z, pa.w, pb.x, pb.y, pb.z, pb.w};
          const float vv[8] = {va.x, va.y, va.z, va.w, vb.x, vb.y, vb.z, vb.w};
#pragma unroll
          for (int q = 0; q < 4; ++q) {
            const float x0 = bf2f((unsigned short)(uu[q] & 0xffffu)) + pv[2*q];
            const float x1 = bf2f((unsigned short)(uu[q] >> 16))     + pv[2*q+1];
            sacc += vv[2*q]   * RCPF(1.0f + EXP2F(x0));
            sacc += vv[2*q+1] * RCPF(1.0f + EXP2F(x1));
          }
        }
        sacc += __shfl_xor(sacc, 1, 64);
        sacc += __shfl_xor(sacc, 2, 64);
        sacc += __shfl_xor(sacc, 4, 64);
        if ((tid & 7) == 0) sc[ts] = sacc + scal[0];
      }
      __syncthreads();

      // P4: softmax over t (wave 0)
      if (tid < 64) {
        const float s0 = sc[tid];
        const float s1 = (tid + 64 < kT) ? sc[tid + 64] : -3.0e38f;
        float m = fmaxf(s0, s1);
        m = redmax64(m);
        const float e0  = EXP2F((s0 - m) * kLog2e);
        const float e1x = (tid + 64 < kT) ? EXP2F((s1 - m) * kLog2e) : 0.0f;
        float sum = e0 + e1x;
        sum = redsum64(sum);
        const float rs = RCPF(sum);
        beta[tid]      = e0  * rs;
        beta[tid + 64] = e1x * rs;     // beta[127] = 0
      }
      __syncthreads();

      // P5: ctx partials: lane e1 accumulates over a 16-t chunk
      {
        float cacc = 0.0f;
#pragma unroll
        for (int q = 0; q < 4; ++q) {
          const float4 b4 = *(const float4*)&beta[ck * 16 + q * 4];
          const int t0 = ck * 16 + q * 4;
          const float x0 = bf2f(xb[(t0 + 0) * 128 + e1]);
          const float x1 = bf2f(xb[(t0 + 1) * 128 + e1]);
          const float x2 = bf2f(xb[(t0 + 2) * 128 + e1]);
          const float x3 = bf2f(xb[(t0 + 3) * 128 + e1]);
          cacc += b4.x*x0 + b4.y*x1 + b4.z*x2 + b4.w*x3;
        }
        part[ck * 128 + e1] = cacc;
      }
      __syncthreads();

      // P6: ctx reduce (lanes 0-127) || y_tilde from partials (wave 2)
      if (tid < 128) {
        float cs = 0.0f;
#pragma unroll
        for (int k = 0; k < 8; ++k) cs += part[k * 128 + tid];
        ctxl[tid] = cs;
      }
      if (tid >= 128 && tid < 192) {
        const int l = tid - 128;
        float ya = 0.0f;
#pragma unroll
        for (int k = 0; k < 8; ++k)
          ya += part[k * 128 + l] * wwl[l] + part[k * 128 + l + 64] * wwl[l + 64];
        ya = redsum64(ya);
        if (l == 0) scal[1] = ya + wwl[128] * yrow[s] + wwl[129];
      }
      __syncthreads();

      // P7: gate nonlinearities (role uniform per wave: i,f,g~,o)
      if (tid < 512) {
        const float gate = ghsum + scal[1] * wihr;
        const int role = tid >> 7;
        float a;
        if (role == 2) {  // tanh
          a = 1.0f - 2.0f * RCPF(1.0f + EXP2F(gate * kK2));
        } else {          // sigmoid
          a = RCPF(1.0f + EXP2F(-gate * kLog2e));
        }
        act[tid] = a;
      }
      __syncthreads();

      // P8: LSTM state update
      if (tid < 128) {
        const float cold = hc[128 + tid];
        const float cn = act[128 + tid] * cold + act[tid] * act[256 + tid];
        const float th = 1.0f - 2.0f * RCPF(1.0f + EXP2F(cn * kK2));
        hc[tid] = act[384 + tid] * th;
        hc[128 + tid] = cn;
      }
      __syncthreads();
    }  // steps

    // ---- final ctx in fp32 from global X (protects the direct fc path) ----
    {
      float cacc = 0.0f;
#pragma unroll
      for (int q = 0; q < 16; ++q) {
        const int t = ck * 16 + q;
        if (t < kT) cacc += beta[t] * Xb[t * 128 + e1];
      }
      part[ck * 128 + e1] = cacc;
    }
    __syncthreads();
    if (tid < 128) {
      float cs = 0.0f;
#pragma unroll
      for (int k = 0; k < 8; ++k) cs += part[k * 128 + tid];
      ctxl[tid] = cs;
    }
    __syncthreads();
    if (tid < 64) {
      float a = hc[tid] * fcw[tid] + hc[tid + 64] * fcw[tid + 64]
              + ctxl[tid] * fcw[128 + tid] + ctxl[tid + 64] * fcw[192 + tid];
      a = redsum64(a);
      if (tid == 0) out[b] = a + fcb[0];
    }
  }  // batch loop
}
}  // namespace

extern "C" void kernel_launch(void* const* d_in, const int* in_sizes, int n_in,
                              void* d_out, int out_size, void* d_ws, size_t ws_size,
                              hipStream_t stream) {
  (void)in_sizes; (void)n_in; (void)d_ws; (void)ws_size; (void)out_size;
  const float* Xg    = (const float*)d_in[0];
  const float* yh    = (const float*)d_in[1];
  const float* vdw   = (const float*)d_in[2];
  const float* vdb   = (const float*)d_in[3];
  const float* Wdhs  = (const float*)d_in[4];
  const float* Wdhsb = (const float*)d_in[5];
  const float* Udw   = (const float*)d_in[6];
  const float* Udb   = (const float*)d_in[7];
  const float* ww    = (const float*)d_in[8];
  const float* wb    = (const float*)d_in[9];
  const float* Wih   = (const float*)d_in[10];
  const float* Whh   = (const float*)d_in[11];
  const float* bih   = (const float*)d_in[12];
  const float* bhh   = (const float*)d_in[13];
  const float* fcww  = (const float*)d_in[14];
  const float* fcb   = (const float*)d_in[15];
  float* out = (float*)d_out;

  hipFuncSetAttribute((const void*)decoder_kernel,
                      hipFuncAttributeMaxDynamicSharedMemorySize, kSmemBytes);
  decoder_kernel<<<dim3(kNWG), dim3(1024), kSmemBytes, stream>>>(
      Xg, yh, vdw, vdb, Wdhs, Wdhsb, Udw, Udb, ww, wb,
      Wih, Whh, bih, bhh, fcww, fcb, out);
}

// Round 3
// 12279.510 us; speedup vs baseline: 2.9287x; 1.9280x over previous
//
#include <hip/hip_runtime.h>
#include <hip/hip_bf16.h>

#if __has_builtin(__builtin_amdgcn_exp2f)
#define EXP2F(x) __builtin_amdgcn_exp2f(x)
#else
#define EXP2F(x) exp2f(x)
#endif
#if __has_builtin(__builtin_amdgcn_rcpf)
#define RCPF(x) __builtin_amdgcn_rcpf(x)
#else
#define RCPF(x) (1.0f/(x))
#endif

typedef _Float16 h2f16 __attribute__((ext_vector_type(2)));

namespace {
constexpr int   kT   = 127;
constexpr int   kE   = 128;
constexpr int   kB   = 4096;
constexpr int   kNWG = 256;
constexpr int   kBPW = kB / kNWG;          // 16 batch elements per workgroup
constexpr float kLog2e = 1.4426950408889634f;
constexpr float kK2    = 2.8853900817779268f;   // 2*log2(e)
constexpr int   kSmemBytes = 77616;

__device__ __forceinline__ unsigned int packf16(float a, float b) {
  h2f16 h = { (_Float16)a, (_Float16)b };
  return __builtin_bit_cast(unsigned int, h);
}
__device__ __forceinline__ float lo16f(unsigned int u) {
  h2f16 h = __builtin_bit_cast(h2f16, u); return (float)h.x;
}
__device__ __forceinline__ float hi16f(unsigned int u) {
  h2f16 h = __builtin_bit_cast(h2f16, u); return (float)h.y;
}

#if __has_builtin(__builtin_amdgcn_fdot2)
__device__ __forceinline__ float fdot2f(unsigned int a, unsigned int b, float c) {
  return __builtin_amdgcn_fdot2(__builtin_bit_cast(h2f16, a),
                                __builtin_bit_cast(h2f16, b), c, false);
}
#else
__device__ __forceinline__ float fdot2f(unsigned int a, unsigned int b, float c) {
  h2f16 ha = __builtin_bit_cast(h2f16, a), hb = __builtin_bit_cast(h2f16, b);
  return c + (float)ha.x * (float)hb.x + (float)ha.y * (float)hb.y;
}
#endif

__device__ __forceinline__ float redsum64(float a) {
#pragma unroll
  for (int m = 1; m < 64; m <<= 1) a += __shfl_xor(a, m, 64);
  return a;
}
__device__ __forceinline__ float redmax64(float a) {
#pragma unroll
  for (int m = 1; m < 64; m <<= 1) a = fmaxf(a, __shfl_xor(a, m, 64));
  return a;
}

__global__ __launch_bounds__(1024, 4) void decoder_kernel(
    const float* __restrict__ Xg,    // [B,127,128]
    const float* __restrict__ yh,    // [B,127]
    const float* __restrict__ vdw,   // [128]
    const float* __restrict__ vdb,   // [1]
    const float* __restrict__ Wdhs,  // [128,256]
    const float* __restrict__ Wdhsb, // [128]
    const float* __restrict__ Udw,   // [128,128]
    const float* __restrict__ Udb,   // [128]
    const float* __restrict__ ww,    // [129]
    const float* __restrict__ wb,    // [1]
    const float* __restrict__ Wih,   // [512]
    const float* __restrict__ Whh,   // [512,128]
    const float* __restrict__ bih,   // [512]
    const float* __restrict__ bhh,   // [512]
    const float* __restrict__ fcww,  // [256]
    const float* __restrict__ fcb,   // [1]
    float* __restrict__ out)         // [B]
{
  extern __shared__ char smem[];
  unsigned int* u2u  = (unsigned int*)smem;            // [128][64] f16-pairs (K2-prescaled U, 16B-chunk XOR swizzle)
  unsigned int* xbT  = (unsigned int*)(smem + 32768);  // [128 e][64 t2] f16 (x[2t2],x[2t2+1]), t2 XOR-swizzled by e&63
  float* hl    = (float*)(smem + 65536);  // [128]  h fp32 (for final fc)
  float* p2    = hl    + 128;             // [128]
  float* sc    = p2    + 128;             // [128]
  float* beta  = sc    + 128;             // [128]  fp32 (final ctx)
  float* part  = beta  + 128;             // [8*128]
  float* act   = part  + 1024;            // [512]  gate partials / activations
  float* ctxl  = act   + 512;             // [128]
  float* wwl   = ctxl  + 128;             // [132]  w_w(129) + w_b at [129]
  float* fcw   = wwl   + 132;             // [256]
  float* wdb_l = fcw   + 256;             // [128]
  float* yrow  = wdb_l + 128;             // [128]
  float* scal  = yrow  + 128;             // [8]    [0]=C0, [1]=y_tilde
  unsigned int* hc2   = (unsigned int*)(scal + 8);     // [128] f16 pairs: h2[64], c2[64]
  unsigned int* beta2 = hc2 + 128;                     // [64]  f16 pairs of beta

  const int tid = threadIdx.x;
  const int g   = tid & 511;          // gate index role
  const int dh  = tid >> 9;           // d-half for W_hh
  const int e1  = tid & 127;          // e index role
  const int ck  = (tid >> 7) & 7;     // 32-col chunk (proj) / 16-t chunk (ctx)
  const int ts  = tid >> 3;           // t for scores (valid < 127)
  const int ec  = (tid & 7) * 16;     // e chunk for scores

  // ---- persistent per-lane weights, f16-packed (66 VGPRs, pinned) ----
  unsigned int whh2[32];
#pragma unroll
  for (int p = 0; p < 32; ++p)
    whh2[p] = packf16(Whh[g * 128 + dh * 64 + 2 * p], Whh[g * 128 + dh * 64 + 2 * p + 1]);
  unsigned int wdr2[16];
#pragma unroll
  for (int j = 0; j < 16; ++j)
    wdr2[j] = packf16(Wdhs[e1 * 256 + ck * 32 + 2 * j], Wdhs[e1 * 256 + ck * 32 + 2 * j + 1]);
  float v2r[16];
#pragma unroll
  for (int j = 0; j < 16; ++j) v2r[j] = -2.0f * vdw[ec + j];
  float bihh = bih[g] + bhh[g];
  float wihr = Wih[g];
#pragma unroll
  for (int p = 0; p < 32; ++p) asm volatile("" : "+v"(whh2[p]));
#pragma unroll
  for (int j = 0; j < 16; ++j) asm volatile("" : "+v"(wdr2[j]));
#pragma unroll
  for (int j = 0; j < 16; ++j) asm volatile("" : "+v"(v2r[j]));
  asm volatile("" : "+v"(bihh));
  asm volatile("" : "+v"(wihr));

  // ---- one-time constants to LDS ----
  if (tid < 129) wwl[tid] = ww[tid];
  if (tid == 0)  wwl[129] = wb[0];
  if (tid < 256) fcw[tid] = fcww[tid];
  if (tid < 128) wdb_l[tid] = Wdhsb[tid];
  if (tid < 64) {
    float a = vdw[tid] + vdw[tid + 64];
    a = redsum64(a);
    if (tid == 0) scal[0] = a + vdb[0];   // C0 = sum(v) + v_b
  }

  for (int bi = 0; bi < kBPW; ++bi) {
    const int b = blockIdx.x * kBPW + bi;
    const float* Xb = Xg + (size_t)b * (kT * kE);
    float creg = 0.0f;                 // c state, lane-private (tid<128)
    __syncthreads();   // previous batch done with LDS

    // ---- stage xbT (f16 t-pairs, swizzled), yrow, zero h2/c2;
    //      precompute U2 from GLOBAL fp32 X (independent of staging) ----
    {
      const int e = tid & 127, t2b = tid >> 7, em = (tid & 63);
      const int emx = e & 63;
      (void)em;
      for (int t2 = t2b; t2 < 64; t2 += 8) {
        const float a = Xb[(2 * t2) * kE + e];
        const float bq = (t2 == 63) ? 0.0f : Xb[(2 * t2 + 1) * kE + e];
        xbT[e * 64 + (t2 ^ emx)] = packf16(a, bq);
      }
    }
    if (tid < kT)  yrow[tid] = yh[b * kT + tid];
    if (tid < 128) hc2[tid] = 0u;       // h2, c2 = 0

    if (ts < kT) {
      const float* Xrow = Xb + ts * kE;
      const int ts7 = ts & 7;
#pragma unroll
      for (int jh = 0; jh < 2; ++jh) {
        float acc[8];
#pragma unroll
        for (int j = 0; j < 8; ++j) acc[j] = 0.0f;
        for (int k0 = 0; k0 < 128; k0 += 4) {
          const float4 xq = *(const float4*)&Xrow[k0];
#pragma unroll
          for (int j = 0; j < 8; ++j) {
            const float4 wq = *(const float4*)&Udw[(ec + jh * 8 + j) * kE + k0];
            acc[j] += xq.x * wq.x + xq.y * wq.y + xq.z * wq.z + xq.w * wq.w;
          }
        }
        const int c = (ec >> 3) + jh;
        uint4 st;
        st.x = packf16(kK2 * (acc[0] + Udb[ec + jh * 8 + 0]), kK2 * (acc[1] + Udb[ec + jh * 8 + 1]));
        st.y = packf16(kK2 * (acc[2] + Udb[ec + jh * 8 + 2]), kK2 * (acc[3] + Udb[ec + jh * 8 + 3]));
        st.z = packf16(kK2 * (acc[4] + Udb[ec + jh * 8 + 4]), kK2 * (acc[5] + Udb[ec + jh * 8 + 5]));
        st.w = packf16(kK2 * (acc[6] + Udb[ec + jh * 8 + 6]), kK2 * (acc[7] + Udb[ec + jh * 8 + 7]));
        *(uint4*)&u2u[ts * 64 + ((c ^ ts7) << 2)] = st;
      }
    }
    __syncthreads();

    // ================= 127 recurrent steps =================
    for (int s = 0; s < kT; ++s) {
      float ghsum = 0.0f;
      // P1: proj partials (W_dhs) + gate partials (W_hh) via packed-f16 dot2
      float pacc = 0.0f;
#pragma unroll
      for (int q4 = 0; q4 < 4; ++q4) {
        const uint4 h4 = *(const uint4*)&hc2[ck * 16 + q4 * 4];
        pacc = fdot2f(wdr2[q4 * 4 + 0], h4.x, pacc);
        pacc = fdot2f(wdr2[q4 * 4 + 1], h4.y, pacc);
        pacc = fdot2f(wdr2[q4 * 4 + 2], h4.z, pacc);
        pacc = fdot2f(wdr2[q4 * 4 + 3], h4.w, pacc);
      }
      part[tid] = pacc;
      float gacc = 0.0f;
#pragma unroll
      for (int q4 = 0; q4 < 8; ++q4) {
        const uint4 h4 = *(const uint4*)&hc2[dh * 32 + q4 * 4];
        gacc = fdot2f(whh2[q4 * 4 + 0], h4.x, gacc);
        gacc = fdot2f(whh2[q4 * 4 + 1], h4.y, gacc);
        gacc = fdot2f(whh2[q4 * 4 + 2], h4.z, gacc);
        gacc = fdot2f(whh2[q4 * 4 + 3], h4.w, gacc);
      }
      if (dh) act[g] = gacc;          // act[] doubles as gate-partial buffer
      __syncthreads();

      // P2: reduce proj -> p2 (prescaled), combine gate halves into reg
      if (tid < 512) ghsum = gacc + act[g] + bihh;
      if (tid < 128) {
        float ps = wdb_l[tid];
#pragma unroll
        for (int k = 0; k < 8; ++k) ps += part[k * 128 + tid];
        p2[tid] = kK2 * ps;
      }
      __syncthreads();

      // P3: scores[t] = C0 - 2*sum_e v[e] * rcp(1 + exp2(p2[e] + U2[t][e]))
      if (ts < kT) {
        const int ts7 = ts & 7;
        const int c0 = (tid & 7) * 2;
        float sacc = 0.0f;
#pragma unroll
        for (int qh = 0; qh < 2; ++qh) {
          const uint4 uq = *(const uint4*)&u2u[ts * 64 + (((c0 + qh) ^ ts7) << 2)];
          const float4 pa = *(const float4*)&p2[ec + qh * 8];
          const float4 pb = *(const float4*)&p2[ec + qh * 8 + 4];
          const unsigned int uu[4] = {uq.x, uq.y, uq.z, uq.w};
          const float pv[8] = {pa.x, pa.y, pa.z, pa.w, pb.x, pb.y, pb.z, pb.w};
#pragma unroll
          for (int q = 0; q < 4; ++q) {
            const float x0 = lo16f(uu[q]) + pv[2 * q];
            const float x1 = hi16f(uu[q]) + pv[2 * q + 1];
            sacc += v2r[qh * 8 + 2 * q]     * RCPF(1.0f + EXP2F(x0));
            sacc += v2r[qh * 8 + 2 * q + 1] * RCPF(1.0f + EXP2F(x1));
          }
        }
        sacc += __shfl_xor(sacc, 1, 64);
        sacc += __shfl_xor(sacc, 2, 64);
        sacc += __shfl_xor(sacc, 4, 64);
        if ((tid & 7) == 0) sc[ts] = sacc + scal[0];
      }
      __syncthreads();

      // P4: softmax over t (wave 0), produce fp32 beta + f16-pair beta2
      if (tid < 64) {
        const float s0 = sc[tid];
        const float s1 = (tid + 64 < kT) ? sc[tid + 64] : -3.0e38f;
        float m = fmaxf(s0, s1);
        m = redmax64(m);
        const float e0  = EXP2F((s0 - m) * kLog2e);
        const float e1x = (tid + 64 < kT) ? EXP2F((s1 - m) * kLog2e) : 0.0f;
        float sum = e0 + e1x;
        sum = redsum64(sum);
        const float rs = RCPF(sum);
        const float b0 = e0 * rs, b1 = e1x * rs;
        beta[tid]      = b0;
        beta[tid + 64] = b1;            // beta[127] = 0
        const float o0 = __shfl_xor(b0, 1, 64);
        const float o1 = __shfl_xor(b1, 1, 64);
        if ((tid & 1) == 0) {
          beta2[tid >> 1]        = packf16(b0, o0);
          beta2[32 + (tid >> 1)] = packf16(b1, o1);
        }
      }
      __syncthreads();

      // P5: ctx partials via fdot2 over t-pairs (swizzled xbT, conflict-free)
      {
        const int em = e1 & 63;
        float cacc = 0.0f;
#pragma unroll
        for (int q = 0; q < 8; ++q) {
          const int t2 = ck * 8 + q;
          cacc = fdot2f(beta2[t2], xbT[e1 * 64 + (t2 ^ em)], cacc);
        }
        part[tid] = cacc;
      }
      __syncthreads();

      // P6: ctx reduce (lanes 0-127) || y_tilde from partials (wave 2)
      if (tid < 128) {
        float cs = 0.0f;
#pragma unroll
        for (int k = 0; k < 8; ++k) cs += part[k * 128 + tid];
        ctxl[tid] = cs;
      }
      if (tid >= 128 && tid < 192) {
        const int l = tid - 128;
        float ya = 0.0f;
#pragma unroll
        for (int k = 0; k < 8; ++k)
          ya += part[k * 128 + l] * wwl[l] + part[k * 128 + l + 64] * wwl[l + 64];
        ya = redsum64(ya);
        if (l == 0) scal[1] = ya + wwl[128] * yrow[s] + wwl[129];
      }
      __syncthreads();

      // P7: gate nonlinearities (role uniform per wave: i,f,g~,o)
      if (tid < 512) {
        const float gate = ghsum + scal[1] * wihr;
        const int role = tid >> 7;
        float a;
        if (role == 2) {  // tanh
          a = 1.0f - 2.0f * RCPF(1.0f + EXP2F(gate * kK2));
        } else {          // sigmoid
          a = RCPF(1.0f + EXP2F(-gate * kLog2e));
        }
        act[tid] = a;
      }
      __syncthreads();

      // P8: LSTM state update; h fp32 to LDS, h/c f16-pairs to hc2, c in reg
      if (tid < 128) {
        const float cn = act[128 + tid] * creg + act[tid] * act[256 + tid];
        const float th = 1.0f - 2.0f * RCPF(1.0f + EXP2F(cn * kK2));
        const float hn = act[384 + tid] * th;
        creg = cn;
        hl[tid] = hn;
        const float ho = __shfl_xor(hn, 1, 64);
        const float co = __shfl_xor(cn, 1, 64);
        if ((tid & 1) == 0) {
          hc2[tid >> 1]      = packf16(hn, ho);
          hc2[64 + (tid >> 1)] = packf16(cn, co);
        }
      }
      __syncthreads();
    }  // steps

    // ---- final ctx in fp32 from global X (protects the direct fc path) ----
    {
      float cacc = 0.0f;
#pragma unroll
      for (int q = 0; q < 16; ++q) {
        const int t = ck * 16 + q;
        if (t < kT) cacc += beta[t] * Xb[t * 128 + e1];
      }
      part[tid] = cacc;
    }
    __syncthreads();
    if (tid < 128) {
      float cs = 0.0f;
#pragma unroll
      for (int k = 0; k < 8; ++k) cs += part[k * 128 + tid];
      ctxl[tid] = cs;
    }
    __syncthreads();
    if (tid < 64) {
      float a = hl[tid] * fcw[tid] + hl[tid + 64] * fcw[tid + 64]
              + ctxl[tid] * fcw[128 + tid] + ctxl[tid + 64] * fcw[192 + tid];
      a = redsum64(a);
      if (tid == 0) out[b] = a + fcb[0];
    }
  }  // batch loop
}
}  // namespace

extern "C" void kernel_launch(void* const* d_in, const int* in_sizes, int n_in,
                              void* d_out, int out_size, void* d_ws, size_t ws_size,
                              hipStream_t stream) {
  (void)in_sizes; (void)n_in; (void)d_ws; (void)ws_size; (void)out_size;
  const float* Xg    = (const float*)d_in[0];
  const float* yh    = (const float*)d_in[1];
  const float* vdw   = (const float*)d_in[2];
  const float* vdb   = (const float*)d_in[3];
  const float* Wdhs  = (const float*)d_in[4];
  const float* Wdhsb = (const float*)d_in[5];
  const float* Udw   = (const float*)d_in[6];
  const float* Udb   = (const float*)d_in[7];
  const float* ww    = (const float*)d_in[8];
  const float* wb    = (const float*)d_in[9];
  const float* Wih   = (const float*)d_in[10];
  const float* Whh   = (const float*)d_in[11];
  const float* bih   = (const float*)d_in[12];
  const float* bhh   = (const float*)d_in[13];
  const float* fcww  = (const float*)d_in[14];
  const float* fcb   = (const float*)d_in[15];
  float* out = (float*)d_out;

  hipFuncSetAttribute((const void*)decoder_kernel,
                      hipFuncAttributeMaxDynamicSharedMemorySize, kSmemBytes);
  decoder_kernel<<<dim3(kNWG), dim3(1024), kSmemBytes, stream>>>(
      Xg, yh, vdw, vdb, Wdhs, Wdhsb, Udw, Udb, ww, wb,
      Wih, Whh, bih, bhh, fcww, fcb, out);
}